// Round 8
// baseline (113.294 us; speedup 1.0000x reference)
//
#include <hip/hip_runtime.h>
#include <math.h>

typedef __attribute__((ext_vector_type(8))) short short8;
typedef __attribute__((ext_vector_type(4))) float floatx4;

__device__ __forceinline__ unsigned short f2bf(float f) {
    unsigned int u = __builtin_bit_cast(unsigned int, f);
    u += 0x7FFFu + ((u >> 16) & 1u);   // round-to-nearest-even
    return (unsigned short)(u >> 16);
}

// Pack 8 consecutive f32 into a bf16 short8 (RNE, same rounding as f2bf).
__device__ __forceinline__ short8 cvt8(const float4 a, const float4 b) {
    short8 r;
    r[0] = (short)f2bf(a.x); r[1] = (short)f2bf(a.y);
    r[2] = (short)f2bf(a.z); r[3] = (short)f2bf(a.w);
    r[4] = (short)f2bf(b.x); r[5] = (short)f2bf(b.y);
    r[6] = (short)f2bf(b.z); r[7] = (short)f2bf(b.w);
    return r;
}

// ---------------------------------------------------------------------------
// ws layout: qkvf f32 [1536][512] (q 0-511, k 512-1023, v 1024-1535);
//            attb bf16 [512][512] ([t][d], scattered writes from attn).
// ---------------------------------------------------------------------------

// ---------------------------------------------------------------------------
// Kernel 1: qkv GEMM, f32 inputs, in-register bf16 cvt, LDS-free wave tiles.
// C[o'][t] = sum_d W[o'][d] * x[t][d].  One 64-thr block = one 32x32 tile.
// Grid 768: mt = bx>>4 (0..47 -> Wq/Wk/Wv rows), nt = bx&15 (t-tile).
// ---------------------------------------------------------------------------
__global__ __launch_bounds__(64) void qkv_gemm(
    const float* __restrict__ x,  const float* __restrict__ Wq,
    const float* __restrict__ Wk, const float* __restrict__ Wv,
    float* __restrict__ qkvf)
{
    const int lane = threadIdx.x;
    const int quad = lane >> 4, l15 = lane & 15;
    const int mt = blockIdx.x >> 4;            // 0..47
    const int nt = blockIdx.x & 15;            // 0..15
    const float* W = (mt < 16) ? Wq : (mt < 32) ? Wk : Wv;
    const int m0 = (mt & 15) * 32;             // row within W
    const int n0 = nt * 32;

    const float* a0 = W + (m0 + l15) * 512 + quad * 8;
    const float* a1 = a0 + 16 * 512;
    const float* b0 = x + (n0 + l15) * 512 + quad * 8;
    const float* b1 = b0 + 16 * 512;

    floatx4 acc[2][2] = {{{0.f,0.f,0.f,0.f},{0.f,0.f,0.f,0.f}},
                         {{0.f,0.f,0.f,0.f},{0.f,0.f,0.f,0.f}}};

    #pragma unroll 4
    for (int kc = 0; kc < 512; kc += 32) {
        const short8 av0 = cvt8(*(const float4*)(a0 + kc), *(const float4*)(a0 + kc + 4));
        const short8 av1 = cvt8(*(const float4*)(a1 + kc), *(const float4*)(a1 + kc + 4));
        const short8 bv0 = cvt8(*(const float4*)(b0 + kc), *(const float4*)(b0 + kc + 4));
        const short8 bv1 = cvt8(*(const float4*)(b1 + kc), *(const float4*)(b1 + kc + 4));
        acc[0][0] = __builtin_amdgcn_mfma_f32_16x16x32_bf16(av0, bv0, acc[0][0], 0, 0, 0);
        acc[0][1] = __builtin_amdgcn_mfma_f32_16x16x32_bf16(av0, bv1, acc[0][1], 0, 0, 0);
        acc[1][0] = __builtin_amdgcn_mfma_f32_16x16x32_bf16(av1, bv0, acc[1][0], 0, 0, 0);
        acc[1][1] = __builtin_amdgcn_mfma_f32_16x16x32_bf16(av1, bv1, acc[1][1], 0, 0, 0);
    }

    // C/D layout: row = quad*4 + r, col = lane&15 (m89-verified)
    const int orow = mt * 32;   // global o' base for this block
    #pragma unroll
    for (int mtt = 0; mtt < 2; ++mtt)
        #pragma unroll
        for (int ntt = 0; ntt < 2; ++ntt) {
            const int grow = orow + mtt * 16 + quad * 4;
            const int gcol = n0 + ntt * 16 + l15;
            #pragma unroll
            for (int r = 0; r < 4; ++r)
                qkvf[(grow + r) * 512 + gcol] = acc[mtt][ntt][r];
        }
}

// ---------------------------------------------------------------------------
// Kernel 2: fused RoPE + per-channel scalar causal attention. IPT=2.
// Block = one channel (512 blocks), 256 threads; thread owns i0=tid, i1=tid+256.
// Wave w phases (wave-uniform bounds, branch-free bodies):
//   P1: j<64w both unmasked; P2: boundary i0 / unmasked i1;
//   P3: i1-only unmasked; P4: boundary i1.  Masks: jj+u <= lane.
// No max-subtraction (|q*k/8| small; exp safe; same math as ref).
// ---------------------------------------------------------------------------
__global__ __launch_bounds__(256) void attn_rope2(
    const float* __restrict__ qkv, unsigned short* __restrict__ attb)
{
    const int ch   = blockIdx.x;
    const int tid  = threadIdx.x;
    const int w    = tid >> 6;
    const int lane = tid & 63;
    const int p    = ch ^ 256;
    const float sgn = (ch < 256) ? -1.f : 1.f;

    __shared__ float ks_[512];
    __shared__ float vs_[512];
    __shared__ float cs_[512];
    __shared__ float sn_[512];

    const float* __restrict__ qg = qkv;
    const float* __restrict__ kg = qkv + 262144;
    const float* __restrict__ vg = qkv + 524288;

    const float inv_freq = powf(10000.f, -(float)(ch & 31) * (1.f / 32.f));

    #pragma unroll
    for (int h = 0; h < 2; ++h) {
        const int t = tid + h * 256;
        float sn, cs;
        sincosf((float)t * inv_freq, &sn, &cs);
        ks_[t] = (kg[ch * 512 + t] * cs + sgn * kg[p * 512 + t] * sn) * 0.125f;
        vs_[t] = vg[ch * 512 + t];
        cs_[t] = cs;
        sn_[t] = sn;
    }
    __syncthreads();

    const int i0 = tid, i1 = tid + 256;
    const float q0 = qg[ch * 512 + i0] * cs_[i0] + sgn * qg[p * 512 + i0] * sn_[i0];
    const float q1 = qg[ch * 512 + i1] * cs_[i1] + sgn * qg[p * 512 + i1] * sn_[i1];

    float l0 = 0.f, a0 = 0.f, l1 = 0.f, a1 = 0.f;
    const int jw = w * 64;   // wave-uniform

    for (int j = 0; j < jw; j += 4) {
        const float4 k4 = *(const float4*)&ks_[j];
        const float4 v4 = *(const float4*)&vs_[j];
        float e;
        e = __expf(q0 * k4.x); l0 += e; a0 = fmaf(e, v4.x, a0);
        e = __expf(q1 * k4.x); l1 += e; a1 = fmaf(e, v4.x, a1);
        e = __expf(q0 * k4.y); l0 += e; a0 = fmaf(e, v4.y, a0);
        e = __expf(q1 * k4.y); l1 += e; a1 = fmaf(e, v4.y, a1);
        e = __expf(q0 * k4.z); l0 += e; a0 = fmaf(e, v4.z, a0);
        e = __expf(q1 * k4.z); l1 += e; a1 = fmaf(e, v4.z, a1);
        e = __expf(q0 * k4.w); l0 += e; a0 = fmaf(e, v4.w, a0);
        e = __expf(q1 * k4.w); l1 += e; a1 = fmaf(e, v4.w, a1);
    }
    #pragma unroll
    for (int jj = 0; jj < 64; jj += 4) {
        const float4 k4 = *(const float4*)&ks_[jw + jj];
        const float4 v4 = *(const float4*)&vs_[jw + jj];
        float e;
        e = (jj + 0 <= lane) ? __expf(q0 * k4.x) : 0.f; l0 += e; a0 = fmaf(e, v4.x, a0);
        e = (jj + 1 <= lane) ? __expf(q0 * k4.y) : 0.f; l0 += e; a0 = fmaf(e, v4.y, a0);
        e = (jj + 2 <= lane) ? __expf(q0 * k4.z) : 0.f; l0 += e; a0 = fmaf(e, v4.z, a0);
        e = (jj + 3 <= lane) ? __expf(q0 * k4.w) : 0.f; l0 += e; a0 = fmaf(e, v4.w, a0);
        e = __expf(q1 * k4.x); l1 += e; a1 = fmaf(e, v4.x, a1);
        e = __expf(q1 * k4.y); l1 += e; a1 = fmaf(e, v4.y, a1);
        e = __expf(q1 * k4.z); l1 += e; a1 = fmaf(e, v4.z, a1);
        e = __expf(q1 * k4.w); l1 += e; a1 = fmaf(e, v4.w, a1);
    }
    for (int j = jw + 64; j < 256 + jw; j += 4) {
        const float4 k4 = *(const float4*)&ks_[j];
        const float4 v4 = *(const float4*)&vs_[j];
        float e;
        e = __expf(q1 * k4.x); l1 += e; a1 = fmaf(e, v4.x, a1);
        e = __expf(q1 * k4.y); l1 += e; a1 = fmaf(e, v4.y, a1);
        e = __expf(q1 * k4.z); l1 += e; a1 = fmaf(e, v4.z, a1);
        e = __expf(q1 * k4.w); l1 += e; a1 = fmaf(e, v4.w, a1);
    }
    #pragma unroll
    for (int jj = 0; jj < 64; jj += 4) {
        const float4 k4 = *(const float4*)&ks_[256 + jw + jj];
        const float4 v4 = *(const float4*)&vs_[256 + jw + jj];
        float e;
        e = (jj + 0 <= lane) ? __expf(q1 * k4.x) : 0.f; l1 += e; a1 = fmaf(e, v4.x, a1);
        e = (jj + 1 <= lane) ? __expf(q1 * k4.y) : 0.f; l1 += e; a1 = fmaf(e, v4.y, a1);
        e = (jj + 2 <= lane) ? __expf(q1 * k4.z) : 0.f; l1 += e; a1 = fmaf(e, v4.z, a1);
        e = (jj + 3 <= lane) ? __expf(q1 * k4.w) : 0.f; l1 += e; a1 = fmaf(e, v4.w, a1);
    }

    attb[i0 * 512 + ch] = f2bf(a0 / l0);   // attT[t][d] bf16, scattered column
    attb[i1 * 512 + ch] = f2bf(a1 / l1);
}

// ---------------------------------------------------------------------------
// Kernel 3: outproj. out[t][o] = sum_d attT[t][d] * Wo[o][d].
// A = attb (bf16, direct short8 loads), B = Wo (f32, in-register cvt).
// One 64-thr block = one 32x32 tile; grid 256: mt = bx>>4 (t), nt = bx&15 (o).
// ---------------------------------------------------------------------------
__global__ __launch_bounds__(64) void outproj(
    const unsigned short* __restrict__ attb, const float* __restrict__ Wo,
    float* __restrict__ out)
{
    const int lane = threadIdx.x;
    const int quad = lane >> 4, l15 = lane & 15;
    const int m0 = (blockIdx.x >> 4) * 32;     // t
    const int n0 = (blockIdx.x & 15) * 32;     // o

    const unsigned short* a0 = attb + (m0 + l15) * 512 + quad * 8;
    const unsigned short* a1 = a0 + 16 * 512;
    const float* b0 = Wo + (n0 + l15) * 512 + quad * 8;
    const float* b1 = b0 + 16 * 512;

    floatx4 acc[2][2] = {{{0.f,0.f,0.f,0.f},{0.f,0.f,0.f,0.f}},
                         {{0.f,0.f,0.f,0.f},{0.f,0.f,0.f,0.f}}};

    #pragma unroll 4
    for (int kc = 0; kc < 512; kc += 32) {
        const short8 av0 = *(const short8*)(a0 + kc);
        const short8 av1 = *(const short8*)(a1 + kc);
        const short8 bv0 = cvt8(*(const float4*)(b0 + kc), *(const float4*)(b0 + kc + 4));
        const short8 bv1 = cvt8(*(const float4*)(b1 + kc), *(const float4*)(b1 + kc + 4));
        acc[0][0] = __builtin_amdgcn_mfma_f32_16x16x32_bf16(av0, bv0, acc[0][0], 0, 0, 0);
        acc[0][1] = __builtin_amdgcn_mfma_f32_16x16x32_bf16(av0, bv1, acc[0][1], 0, 0, 0);
        acc[1][0] = __builtin_amdgcn_mfma_f32_16x16x32_bf16(av1, bv0, acc[1][0], 0, 0, 0);
        acc[1][1] = __builtin_amdgcn_mfma_f32_16x16x32_bf16(av1, bv1, acc[1][1], 0, 0, 0);
    }

    #pragma unroll
    for (int mtt = 0; mtt < 2; ++mtt)
        #pragma unroll
        for (int ntt = 0; ntt < 2; ++ntt) {
            const int grow = m0 + mtt * 16 + quad * 4;   // t
            const int gcol = n0 + ntt * 16 + l15;        // o
            #pragma unroll
            for (int r = 0; r < 4; ++r)
                out[(grow + r) * 512 + gcol] = acc[mtt][ntt][r];
        }
}

// ---------------------------------------------------------------------------
extern "C" void kernel_launch(void* const* d_in, const int* in_sizes, int n_in,
                              void* d_out, int out_size, void* d_ws, size_t ws_size,
                              hipStream_t stream)
{
    const float* x  = (const float*)d_in[0];
    const float* Wq = (const float*)d_in[1];
    const float* Wk = (const float*)d_in[2];
    const float* Wv = (const float*)d_in[3];
    const float* Wo = (const float*)d_in[4];
    float* out = (float*)d_out;

    float* qkvf = (float*)d_ws;                                   // 786432 f32
    unsigned short* attb = (unsigned short*)(qkvf + 786432);      // 262144 bf16

    qkv_gemm<<<768, 64, 0, stream>>>(x, Wq, Wk, Wv, qkvf);
    attn_rope2<<<512, 256, 0, stream>>>(qkvf, attb);
    outproj<<<256, 64, 0, stream>>>(attb, Wo, out);
}

// Round 9
// 106.711 us; speedup vs baseline: 1.0617x; 1.0617x over previous
//
#include <hip/hip_runtime.h>
#include <math.h>

typedef __attribute__((ext_vector_type(8))) short short8;
typedef __attribute__((ext_vector_type(4))) float floatx4;

__device__ __forceinline__ unsigned short f2bf(float f) {
    unsigned int u = __builtin_bit_cast(unsigned int, f);
    u += 0x7FFFu + ((u >> 16) & 1u);   // round-to-nearest-even
    return (unsigned short)(u >> 16);
}

// ---------------------------------------------------------------------------
// ws layout:
//   Wallb bf16 [1536][512]  (Wq 0-511, Wk 512-1023, Wv 1024-1535)
//   xb    bf16 [512][512]   ([t][d])
//   Wob   bf16 [512][512]   ([o][d])
//   attb  bf16 [512][512]   ([t][d], scattered writes from attn)
//   qkvf  f32  [1536][512]  ([o'][t])
// ---------------------------------------------------------------------------

__global__ __launch_bounds__(256) void cvt_bf16(
    const float* __restrict__ x,  const float* __restrict__ Wq,
    const float* __restrict__ Wk, const float* __restrict__ Wv,
    const float* __restrict__ Wo, unsigned short* __restrict__ Wallb,
    unsigned short* __restrict__ xb, unsigned short* __restrict__ Wob)
{
    const float* src; unsigned short* dst;
    switch (blockIdx.y) {
        case 0: src = Wq; dst = Wallb;          break;
        case 1: src = Wk; dst = Wallb + 262144; break;
        case 2: src = Wv; dst = Wallb + 524288; break;
        case 3: src = x;  dst = xb;             break;
        default: src = Wo; dst = Wob;           break;
    }
    const int i4 = (blockIdx.x * 256 + threadIdx.x) * 4;
    const float4 v = *(const float4*)(src + i4);
    ushort4 o;
    o.x = f2bf(v.x); o.y = f2bf(v.y); o.z = f2bf(v.z); o.w = f2bf(v.w);
    *(ushort4*)(dst + i4) = o;
}

// ---------------------------------------------------------------------------
// bf16 MFMA GEMM (R3-proven): C[m][n] = sum_k A[m][k]*B[n][k], K=512, ldc=512.
// Block 256 thr = 4 waves; 64x64 tile; wave = 2x2 x mfma_16x16x32_bf16.
// BK=64, global_load_lds width 16, XOR-swizzled k-chunks (conflict-free).
// ---------------------------------------------------------------------------
__global__ __launch_bounds__(256) void gemm_bt(
    const unsigned short* __restrict__ A,   // [M][512] bf16
    const unsigned short* __restrict__ B,   // [N][512] bf16
    float* __restrict__ C)                  // [M][512] f32
{
    __shared__ unsigned short As[64 * 64];
    __shared__ unsigned short Bs[64 * 64];

    const int tid  = threadIdx.x;
    const int lane = tid & 63;
    const int w    = tid >> 6;            // wave 0..3
    const int m0   = blockIdx.y * 64;
    const int n0   = blockIdx.x * 64;
    const int wm   = (w >> 1) * 32;
    const int wn   = (w & 1) * 32;

    const int srow8 = w * 8 + (lane >> 3);  // staging row within 32-row round
    const int c8    = lane & 7;             // 16B chunk index within 64-k row

    floatx4 acc[2][2] = {{{0.f,0.f,0.f,0.f},{0.f,0.f,0.f,0.f}},
                         {{0.f,0.f,0.f,0.f},{0.f,0.f,0.f,0.f}}};

    const int quad = lane >> 4;
    const int l15  = lane & 15;

    for (int kc = 0; kc < 512; kc += 64) {
        #pragma unroll
        for (int rr = 0; rr < 2; ++rr) {
            const int row  = rr * 32 + srow8;           // 0..63
            const int gcol = kc + ((c8 ^ (row & 7)) * 8);
            const unsigned short* ga = A + (m0 + row) * 512 + gcol;
            const unsigned short* gb = B + (n0 + row) * 512 + gcol;
            __builtin_amdgcn_global_load_lds(
                (const __attribute__((address_space(1))) void*)ga,
                (__attribute__((address_space(3))) void*)&As[(rr * 32 + w * 8) * 64],
                16, 0, 0);
            __builtin_amdgcn_global_load_lds(
                (const __attribute__((address_space(1))) void*)gb,
                (__attribute__((address_space(3))) void*)&Bs[(rr * 32 + w * 8) * 64],
                16, 0, 0);
        }
        __syncthreads();

        #pragma unroll
        for (int ks = 0; ks < 2; ++ks) {
            const int cIdx = ks * 4 + quad;             // 16B chunk 0..7
            short8 a[2], b[2];
            #pragma unroll
            for (int mt = 0; mt < 2; ++mt) {
                const int row = wm + mt * 16 + l15;
                a[mt] = *(const short8*)&As[row * 64 + ((cIdx ^ (row & 7)) * 8)];
            }
            #pragma unroll
            for (int nt = 0; nt < 2; ++nt) {
                const int row = wn + nt * 16 + l15;
                b[nt] = *(const short8*)&Bs[row * 64 + ((cIdx ^ (row & 7)) * 8)];
            }
            #pragma unroll
            for (int mt = 0; mt < 2; ++mt)
                #pragma unroll
                for (int nt = 0; nt < 2; ++nt)
                    acc[mt][nt] = __builtin_amdgcn_mfma_f32_16x16x32_bf16(
                        a[mt], b[nt], acc[mt][nt], 0, 0, 0);
        }
        __syncthreads();
    }

    // C/D layout (m89-verified): row = quad*4 + reg, col = lane&15
    #pragma unroll
    for (int mt = 0; mt < 2; ++mt)
        #pragma unroll
        for (int nt = 0; nt < 2; ++nt) {
            const int grow = m0 + wm + mt * 16 + quad * 4;
            const int gcol = n0 + wn + nt * 16 + l15;
            #pragma unroll
            for (int r = 0; r < 4; ++r)
                C[(grow + r) * 512 + gcol] = acc[mt][nt][r];
        }
}

// ---------------------------------------------------------------------------
// Fused RoPE + per-channel scalar causal attention. IPT=2 (R5-proven).
// Block = one channel (512 blocks), 256 threads; thread owns i0=tid, i1=tid+256.
// Wave w phases (wave-uniform bounds, branch-free bodies):
//   P1: j<64w both unmasked; P2: boundary i0 / unmasked i1;
//   P3: i1-only unmasked; P4: boundary i1.  Masks: jj+u <= lane.
// No max-subtraction (|q*k/8| small; exp safe; same math as ref).
// Output: bf16 attT[t][d] directly (d = ch), no separate transpose pass.
// ---------------------------------------------------------------------------
__global__ __launch_bounds__(256) void attn_rope2(
    const float* __restrict__ qkv, unsigned short* __restrict__ attb)
{
    const int ch   = blockIdx.x;
    const int tid  = threadIdx.x;
    const int w    = tid >> 6;
    const int lane = tid & 63;
    const int p    = ch ^ 256;
    const float sgn = (ch < 256) ? -1.f : 1.f;

    __shared__ float ks_[512];
    __shared__ float vs_[512];
    __shared__ float cs_[512];
    __shared__ float sn_[512];

    const float* __restrict__ qg = qkv;
    const float* __restrict__ kg = qkv + 262144;
    const float* __restrict__ vg = qkv + 524288;

    const float inv_freq = powf(10000.f, -(float)(ch & 31) * (1.f / 32.f));

    #pragma unroll
    for (int h = 0; h < 2; ++h) {
        const int t = tid + h * 256;
        float sn, cs;
        sincosf((float)t * inv_freq, &sn, &cs);
        ks_[t] = (kg[ch * 512 + t] * cs + sgn * kg[p * 512 + t] * sn) * 0.125f;
        vs_[t] = vg[ch * 512 + t];
        cs_[t] = cs;
        sn_[t] = sn;
    }
    __syncthreads();

    const int i0 = tid, i1 = tid + 256;
    const float q0 = qg[ch * 512 + i0] * cs_[i0] + sgn * qg[p * 512 + i0] * sn_[i0];
    const float q1 = qg[ch * 512 + i1] * cs_[i1] + sgn * qg[p * 512 + i1] * sn_[i1];

    float l0 = 0.f, a0 = 0.f, l1 = 0.f, a1 = 0.f;
    const int jw = w * 64;   // wave-uniform

    for (int j = 0; j < jw; j += 4) {
        const float4 k4 = *(const float4*)&ks_[j];
        const float4 v4 = *(const float4*)&vs_[j];
        float e;
        e = __expf(q0 * k4.x); l0 += e; a0 = fmaf(e, v4.x, a0);
        e = __expf(q1 * k4.x); l1 += e; a1 = fmaf(e, v4.x, a1);
        e = __expf(q0 * k4.y); l0 += e; a0 = fmaf(e, v4.y, a0);
        e = __expf(q1 * k4.y); l1 += e; a1 = fmaf(e, v4.y, a1);
        e = __expf(q0 * k4.z); l0 += e; a0 = fmaf(e, v4.z, a0);
        e = __expf(q1 * k4.z); l1 += e; a1 = fmaf(e, v4.z, a1);
        e = __expf(q0 * k4.w); l0 += e; a0 = fmaf(e, v4.w, a0);
        e = __expf(q1 * k4.w); l1 += e; a1 = fmaf(e, v4.w, a1);
    }
    #pragma unroll
    for (int jj = 0; jj < 64; jj += 4) {
        const float4 k4 = *(const float4*)&ks_[jw + jj];
        const float4 v4 = *(const float4*)&vs_[jw + jj];
        float e;
        e = (jj + 0 <= lane) ? __expf(q0 * k4.x) : 0.f; l0 += e; a0 = fmaf(e, v4.x, a0);
        e = (jj + 1 <= lane) ? __expf(q0 * k4.y) : 0.f; l0 += e; a0 = fmaf(e, v4.y, a0);
        e = (jj + 2 <= lane) ? __expf(q0 * k4.z) : 0.f; l0 += e; a0 = fmaf(e, v4.z, a0);
        e = (jj + 3 <= lane) ? __expf(q0 * k4.w) : 0.f; l0 += e; a0 = fmaf(e, v4.w, a0);
        e = __expf(q1 * k4.x); l1 += e; a1 = fmaf(e, v4.x, a1);
        e = __expf(q1 * k4.y); l1 += e; a1 = fmaf(e, v4.y, a1);
        e = __expf(q1 * k4.z); l1 += e; a1 = fmaf(e, v4.z, a1);
        e = __expf(q1 * k4.w); l1 += e; a1 = fmaf(e, v4.w, a1);
    }
    for (int j = jw + 64; j < 256 + jw; j += 4) {
        const float4 k4 = *(const float4*)&ks_[j];
        const float4 v4 = *(const float4*)&vs_[j];
        float e;
        e = __expf(q1 * k4.x); l1 += e; a1 = fmaf(e, v4.x, a1);
        e = __expf(q1 * k4.y); l1 += e; a1 = fmaf(e, v4.y, a1);
        e = __expf(q1 * k4.z); l1 += e; a1 = fmaf(e, v4.z, a1);
        e = __expf(q1 * k4.w); l1 += e; a1 = fmaf(e, v4.w, a1);
    }
    #pragma unroll
    for (int jj = 0; jj < 64; jj += 4) {
        const float4 k4 = *(const float4*)&ks_[256 + jw + jj];
        const float4 v4 = *(const float4*)&vs_[256 + jw + jj];
        float e;
        e = (jj + 0 <= lane) ? __expf(q1 * k4.x) : 0.f; l1 += e; a1 = fmaf(e, v4.x, a1);
        e = (jj + 1 <= lane) ? __expf(q1 * k4.y) : 0.f; l1 += e; a1 = fmaf(e, v4.y, a1);
        e = (jj + 2 <= lane) ? __expf(q1 * k4.z) : 0.f; l1 += e; a1 = fmaf(e, v4.z, a1);
        e = (jj + 3 <= lane) ? __expf(q1 * k4.w) : 0.f; l1 += e; a1 = fmaf(e, v4.w, a1);
    }

    attb[i0 * 512 + ch] = f2bf(a0 / l0);   // attT[t][d] bf16, scattered column
    attb[i1 * 512 + ch] = f2bf(a1 / l1);
}

// ---------------------------------------------------------------------------
extern "C" void kernel_launch(void* const* d_in, const int* in_sizes, int n_in,
                              void* d_out, int out_size, void* d_ws, size_t ws_size,
                              hipStream_t stream)
{
    const float* x  = (const float*)d_in[0];
    const float* Wq = (const float*)d_in[1];
    const float* Wk = (const float*)d_in[2];
    const float* Wv = (const float*)d_in[3];
    const float* Wo = (const float*)d_in[4];
    float* out = (float*)d_out;

    unsigned short* Wallb = (unsigned short*)d_ws;        // 786432 bf16
    unsigned short* xb    = Wallb + 786432;               // 262144
    unsigned short* Wob   = xb + 262144;                  // 262144
    unsigned short* attb  = Wob + 262144;                 // 262144
    float* qkvf = (float*)(attb + 262144);                // 786432 f32

    cvt_bf16<<<dim3(256, 5), 256, 0, stream>>>(x, Wq, Wk, Wv, Wo, Wallb, xb, Wob);
    // qkv: C[o'][t] = sum_d Wall[o'][d] * x[t][d]   (M=1536, N=512)
    gemm_bt<<<dim3(8, 24), 256, 0, stream>>>(Wallb, xb, qkvf);
    attn_rope2<<<512, 256, 0, stream>>>(qkvf, attb);
    // out: C[t][o] = sum_d attT[t][d] * Wo[o][d]    (M=512, N=512)
    gemm_bt<<<dim3(8, 8), 256, 0, stream>>>(attb, Wob, out);
}